// Round 1
// baseline (12350.344 us; speedup 1.0000x reference)
//
#include <hip/hip_runtime.h>
#include <hip/hip_cooperative_groups.h>
#include <math.h>

namespace cg = cooperative_groups;

#define NB 8
#define NN 1024
#define DD 256
#define NP1 1025
#define LDT 1028
#define NSTEPS 100

// ---------------------------------------------------------------- norms ----
__global__ __launch_bounds__(256) void norm_kernel(const float* __restrict__ fA,
                                                   const float* __restrict__ fB,
                                                   float* __restrict__ invA,
                                                   float* __restrict__ invB) {
  int gw = (blockIdx.x * 256 + threadIdx.x) >> 6;  // global wave id, 0..16383
  int lane = threadIdx.x & 63;
  const float* src;
  float* dst;
  int row;
  if (gw < NB * NN) { src = fA; dst = invA; row = gw; }
  else              { src = fB; dst = invB; row = gw - NB * NN; }
  float4 v = *(const float4*)(src + (size_t)row * DD + lane * 4);
  double ss = (double)v.x * v.x + (double)v.y * v.y + (double)v.z * v.z + (double)v.w * v.w;
#pragma unroll
  for (int o = 32; o; o >>= 1) ss += __shfl_xor(ss, o, 64);
  if (lane == 0) dst[row] = (float)(1.0 / sqrt(fmax(ss, 1e-12)));
}

// ------------------------------------------------ GEMM + exp + partial Z ---
__global__ __launch_bounds__(256) void gemm_exp_kernel(const float* __restrict__ fA,
                                                       const float* __restrict__ fB,
                                                       const float* __restrict__ invA,
                                                       const float* __restrict__ invB,
                                                       float* __restrict__ P0,
                                                       float* __restrict__ P0T,
                                                       double* __restrict__ partZ) {
  const int b = blockIdx.z, bx = blockIdx.x, by = blockIdx.y;
  const int row0 = by * 64, col0 = bx * 64;
  const int tid = threadIdx.x;
  const int tx = tid & 15, ty = tid >> 4;
  __shared__ __align__(16) float As[16][68];
  __shared__ __align__(16) float Bs[16][68];
  __shared__ __align__(16) float Ts[64][68];
  __shared__ double zred[256];
  float acc[4][4] = {{0.f}};
  const int lm = tid >> 2, kq = (tid & 3) << 2;
  const float sa = invA[b * NN + row0 + lm];
  const float sb = invB[b * NN + col0 + lm];
  const float* pA = fA + (size_t)(b * NN + row0 + lm) * DD + kq;
  const float* pB = fB + (size_t)(b * NN + col0 + lm) * DD + kq;
  for (int k0 = 0; k0 < DD; k0 += 16) {
    const float4 a4 = *(const float4*)(pA + k0);
    const float4 b4 = *(const float4*)(pB + k0);
    As[kq + 0][lm] = a4.x * sa; As[kq + 1][lm] = a4.y * sa;
    As[kq + 2][lm] = a4.z * sa; As[kq + 3][lm] = a4.w * sa;
    Bs[kq + 0][lm] = b4.x * sb; Bs[kq + 1][lm] = b4.y * sb;
    Bs[kq + 2][lm] = b4.z * sb; Bs[kq + 3][lm] = b4.w * sb;
    __syncthreads();
#pragma unroll
    for (int kk = 0; kk < 16; ++kk) {
      const float4 av = *(const float4*)&As[kk][ty * 4];
      const float4 bv = *(const float4*)&Bs[kk][tx * 4];
      const float ar[4] = {av.x, av.y, av.z, av.w};
      const float br[4] = {bv.x, bv.y, bv.z, bv.w};
#pragma unroll
      for (int a = 0; a < 4; ++a)
#pragma unroll
        for (int e = 0; e < 4; ++e)
          acc[a][e] = fmaf(ar[a], br[e], acc[a][e]);
    }
    __syncthreads();
  }
  // exp(5*clip(S,-3,3)) == exp(-5*clip(-S,-3,3))  (matches reference exactly)
  double zs = 0.0;
#pragma unroll
  for (int a = 0; a < 4; ++a)
#pragma unroll
    for (int e = 0; e < 4; ++e) {
      const float S = acc[a][e];
      const float C = fminf(fmaxf(-S, -3.0f), 3.0f);
      const float p = expf(-5.0f * C);
      acc[a][e] = p;
      zs += (double)p;
    }
  zred[tid] = zs;
  __syncthreads();
#pragma unroll
  for (int o = 128; o; o >>= 1) {
    if (tid < o) zred[tid] += zred[tid + o];
    __syncthreads();
  }
  if (tid == 0) partZ[(b * 16 + by) * 16 + bx] = zred[0];
  // pass A: stage row-major tile, write P0 coalesced (scalar rows of 256B/wave)
#pragma unroll
  for (int a = 0; a < 4; ++a)
#pragma unroll
    for (int e = 0; e < 4; ++e)
      Ts[ty * 4 + a][tx * 4 + e] = acc[a][e];
  __syncthreads();
  {
    const int lane = tid & 63, w = tid >> 6;
    float* P0b = P0 + (size_t)b * NP1 * NP1;
    for (int j = w; j < 64; j += 4)
      P0b[(size_t)(row0 + j) * NP1 + col0 + lane] = Ts[j][lane];
  }
  __syncthreads();
  // pass B: stage transposed tile, write P0T
#pragma unroll
  for (int a = 0; a < 4; ++a)
#pragma unroll
    for (int e = 0; e < 4; ++e)
      Ts[tx * 4 + e][ty * 4 + a] = acc[a][e];
  __syncthreads();
  {
    const int lane = tid & 63, w = tid >> 6;
    float* P0Tb = P0T + (size_t)b * NP1 * LDT;
    for (int j = w; j < 64; j += 4)
      P0Tb[(size_t)(col0 + j) * LDT + row0 + lane] = Ts[j][lane];
  }
}

// ------------------------------------------------------- dustbin borders ---
__global__ __launch_bounds__(1024) void fill_dustbin_kernel(const float* __restrict__ dustbin,
                                                            float* __restrict__ P0,
                                                            float* __restrict__ P0T) {
  const int b = blockIdx.x, tid = threadIdx.x;
  const float d = dustbin[0];
  const float dv = expf(-5.0f * fminf(fmaxf(-d, -3.0f), 3.0f));
  float* P0b = P0 + (size_t)b * NP1 * NP1;
  float* P0Tb = P0T + (size_t)b * NP1 * LDT;
  for (int j = tid; j < NP1; j += 1024) {
    P0b[(size_t)NN * NP1 + j] = dv;   // dustbin row
    P0b[(size_t)j * NP1 + NN] = dv;   // dustbin col (corner written twice, same value)
    P0Tb[(size_t)NN * LDT + j] = dv;
    P0Tb[(size_t)j * LDT + NN] = dv;
  }
}

// ----------------------------------------------------------- init r, c -----
__global__ __launch_bounds__(256) void init_rc_kernel(const double* __restrict__ partZ,
                                                      const float* __restrict__ dustbin,
                                                      float* __restrict__ rbuf,
                                                      float* __restrict__ cbuf) {
  const int b = blockIdx.x, tid = threadIdx.x;
  __shared__ double red[256];
  red[tid] = partZ[b * 256 + tid];
  __syncthreads();
#pragma unroll
  for (int o = 128; o; o >>= 1) {
    if (tid < o) red[tid] += red[tid + o];
    __syncthreads();
  }
  const float d = dustbin[0];
  const float dv = expf(-5.0f * fminf(fmaxf(-d, -3.0f), 3.0f));
  const double Z = red[0] + (double)dv * (double)(2 * NP1 - 1);
  const float rv = (float)(1.0 / Z);
  for (int i = tid; i < NP1; i += 256) {
    rbuf[b * NP1 + i] = rv;   // buffer 0
    cbuf[b * NP1 + i] = 1.0f; // buffer 0
  }
}

// -------------------------------------------- 100 Sinkhorn iterations ------
// P_t = diag(r) * P0 * diag(c).  Per step (both from OLD r,c, matching the
// reference's "row_sum/col_sum from the SAME P"):
//   u_i = (P0 c)_i   -> r'_i = ab_i / u_i
//   v_j = (P0^T r)_j -> c'_j = ab_j / v_j
__global__ __launch_bounds__(1024) void sinkhorn_kernel(const float* __restrict__ P0,
                                                        const float* __restrict__ P0T,
                                                        float* __restrict__ rbuf,
                                                        float* __restrict__ cbuf) {
  cg::grid_group grid = cg::this_grid();
  const int blk = blockIdx.x;
  const int b = blk >> 5, s = blk & 31;
  const int i0 = s * 32;
  const int nrows = (s == 31) ? 33 : 32;  // last slab also owns the dustbin row/col
  const float* P0b = P0 + (size_t)b * NP1 * NP1;
  const float* P0Tb = P0T + (size_t)b * NP1 * LDT;
  __shared__ float sc[NP1];
  __shared__ float sr[NP1];
  const int tid = threadIdx.x;
  const int lane = tid & 63;
  const int wv = tid >> 6;  // 16 waves
  for (int t = 0; t < NSTEPS; ++t) {
    const int pin = t & 1;
    const float* rin = rbuf + pin * NB * NP1 + b * NP1;
    const float* cin = cbuf + pin * NB * NP1 + b * NP1;
    float* rout = rbuf + (pin ^ 1) * NB * NP1 + b * NP1;
    float* cout = cbuf + (pin ^ 1) * NB * NP1 + b * NP1;
    for (int j = tid; j < NP1; j += 1024) { sc[j] = cin[j]; sr[j] = rin[j]; }
    __syncthreads();
    for (int d = wv; d < 2 * nrows; d += 16) {
      const bool isU = (d < nrows);
      const int rr = i0 + (isU ? d : d - nrows);
      const float* rowp = isU ? (P0b + (size_t)rr * NP1) : (P0Tb + (size_t)rr * LDT);
      const float* vec = isU ? sc : sr;
      double acc = 0.0;
      for (int j = lane; j < NP1; j += 64) acc += (double)rowp[j] * (double)vec[j];
#pragma unroll
      for (int o = 32; o; o >>= 1) acc += __shfl_xor(acc, o, 64);
      if (lane == 0) {
        const float ab = (rr == NN) ? (float)NN : 1.0f;
        const float res = (float)((double)ab / acc);
        if (isU) rout[rr] = res;
        else     cout[rr] = res;
      }
    }
    __threadfence();
    grid.sync();
  }
}

// --------------------------------------------------------------- finalize --
__global__ __launch_bounds__(256) void finalize_kernel(float* __restrict__ P,
                                                       const float* __restrict__ rfin,
                                                       const float* __restrict__ cfin) {
  const int bi = blockIdx.x;
  const int b = bi / NP1, i = bi % NP1;
  const float rv = rfin[b * NP1 + i];
  float* row = P + (size_t)b * NP1 * NP1 + (size_t)i * NP1;
  const float* cv = cfin + b * NP1;
  for (int j = threadIdx.x; j < NP1; j += 256) row[j] = rv * row[j] * cv[j];
}

// ---------------------------------------------------------------------------
extern "C" void kernel_launch(void* const* d_in, const int* in_sizes, int n_in,
                              void* d_out, int out_size, void* d_ws, size_t ws_size,
                              hipStream_t stream) {
  const float* fA = (const float*)d_in[0];
  const float* fB = (const float*)d_in[1];
  const float* dustbin = (const float*)d_in[2];

  float* P0 = (float*)d_out;                       // scratch until finalize
  float* P0T = (float*)d_ws;                       // 8*1025*1028 floats
  float* rbuf = P0T + (size_t)NB * NP1 * LDT;      // [2][8][1025]
  float* cbuf = rbuf + 2 * NB * NP1;               // [2][8][1025]
  double* partZ = (double*)(cbuf + 2 * NB * NP1);  // [8][256]
  float* invA = (float*)(partZ + NB * 256);        // [8][1024]
  float* invB = invA + NB * NN;                    // [8][1024]

  norm_kernel<<<4096, 256, 0, stream>>>(fA, fB, invA, invB);

  dim3 g2(16, 16, NB);
  gemm_exp_kernel<<<g2, 256, 0, stream>>>(fA, fB, invA, invB, P0, P0T, partZ);

  fill_dustbin_kernel<<<NB, 1024, 0, stream>>>(dustbin, P0, P0T);
  init_rc_kernel<<<NB, 256, 0, stream>>>(partZ, dustbin, rbuf, cbuf);

  void* args[] = {(void*)&P0, (void*)&P0T, (void*)&rbuf, (void*)&cbuf};
  hipLaunchCooperativeKernel((const void*)sinkhorn_kernel, dim3(256), dim3(1024),
                             args, 0, stream);

  // NSTEPS even -> final r,c land in buffer 0
  finalize_kernel<<<NB * NP1, 256, 0, stream>>>(P0, rbuf, cbuf);
}

// Round 3
// 11166.109 us; speedup vs baseline: 1.1061x; 1.1061x over previous
//
#include <hip/hip_runtime.h>
#include <hip/hip_cooperative_groups.h>
#include <math.h>

namespace cg = cooperative_groups;

#define NB 8
#define NN 1024
#define DD 256
#define NP1 1025
#define LDT 1028
#define NSTEPS 100

// ---------------------------------------------------------------- norms ----
__global__ __launch_bounds__(256) void norm_kernel(const float* __restrict__ fA,
                                                   const float* __restrict__ fB,
                                                   float* __restrict__ invA,
                                                   float* __restrict__ invB) {
  int gw = (blockIdx.x * 256 + threadIdx.x) >> 6;  // global wave id, 0..16383
  int lane = threadIdx.x & 63;
  const float* src;
  float* dst;
  int row;
  if (gw < NB * NN) { src = fA; dst = invA; row = gw; }
  else              { src = fB; dst = invB; row = gw - NB * NN; }
  float4 v = *(const float4*)(src + (size_t)row * DD + lane * 4);
  double ss = (double)v.x * v.x + (double)v.y * v.y + (double)v.z * v.z + (double)v.w * v.w;
#pragma unroll
  for (int o = 32; o; o >>= 1) ss += __shfl_xor(ss, o, 64);
  if (lane == 0) dst[row] = (float)(1.0 / sqrt(fmax(ss, 1e-12)));
}

// ------------------------------------------------ GEMM + exp + partial Z ---
__global__ __launch_bounds__(256) void gemm_exp_kernel(const float* __restrict__ fA,
                                                       const float* __restrict__ fB,
                                                       const float* __restrict__ invA,
                                                       const float* __restrict__ invB,
                                                       float* __restrict__ P0,
                                                       float* __restrict__ P0T,
                                                       double* __restrict__ partZ) {
  const int b = blockIdx.z, bx = blockIdx.x, by = blockIdx.y;
  const int row0 = by * 64, col0 = bx * 64;
  const int tid = threadIdx.x;
  const int tx = tid & 15, ty = tid >> 4;
  __shared__ __align__(16) float As[16][68];
  __shared__ __align__(16) float Bs[16][68];
  __shared__ __align__(16) float Ts[64][68];
  __shared__ double zred[256];
  float acc[4][4] = {{0.f}};
  const int lm = tid >> 2, kq = (tid & 3) << 2;
  const float sa = invA[b * NN + row0 + lm];
  const float sb = invB[b * NN + col0 + lm];
  const float* pA = fA + (size_t)(b * NN + row0 + lm) * DD + kq;
  const float* pB = fB + (size_t)(b * NN + col0 + lm) * DD + kq;
  for (int k0 = 0; k0 < DD; k0 += 16) {
    const float4 a4 = *(const float4*)(pA + k0);
    const float4 b4 = *(const float4*)(pB + k0);
    As[kq + 0][lm] = a4.x * sa; As[kq + 1][lm] = a4.y * sa;
    As[kq + 2][lm] = a4.z * sa; As[kq + 3][lm] = a4.w * sa;
    Bs[kq + 0][lm] = b4.x * sb; Bs[kq + 1][lm] = b4.y * sb;
    Bs[kq + 2][lm] = b4.z * sb; Bs[kq + 3][lm] = b4.w * sb;
    __syncthreads();
#pragma unroll
    for (int kk = 0; kk < 16; ++kk) {
      const float4 av = *(const float4*)&As[kk][ty * 4];
      const float4 bv = *(const float4*)&Bs[kk][tx * 4];
      const float ar[4] = {av.x, av.y, av.z, av.w};
      const float br[4] = {bv.x, bv.y, bv.z, bv.w};
#pragma unroll
      for (int a = 0; a < 4; ++a)
#pragma unroll
        for (int e = 0; e < 4; ++e)
          acc[a][e] = fmaf(ar[a], br[e], acc[a][e]);
    }
    __syncthreads();
  }
  // exp(5*clip(S,-3,3)) == exp(-5*clip(-S,-3,3))  (matches reference exactly)
  double zs = 0.0;
#pragma unroll
  for (int a = 0; a < 4; ++a)
#pragma unroll
    for (int e = 0; e < 4; ++e) {
      const float S = acc[a][e];
      const float C = fminf(fmaxf(-S, -3.0f), 3.0f);
      const float p = expf(-5.0f * C);
      acc[a][e] = p;
      zs += (double)p;
    }
  zred[tid] = zs;
  __syncthreads();
#pragma unroll
  for (int o = 128; o; o >>= 1) {
    if (tid < o) zred[tid] += zred[tid + o];
    __syncthreads();
  }
  if (tid == 0) partZ[(b * 16 + by) * 16 + bx] = zred[0];
  // pass A: stage row-major tile, write P0 coalesced
#pragma unroll
  for (int a = 0; a < 4; ++a)
#pragma unroll
    for (int e = 0; e < 4; ++e)
      Ts[ty * 4 + a][tx * 4 + e] = acc[a][e];
  __syncthreads();
  {
    const int lane = tid & 63, w = tid >> 6;
    float* P0b = P0 + (size_t)b * NP1 * NP1;
    for (int j = w; j < 64; j += 4)
      P0b[(size_t)(row0 + j) * NP1 + col0 + lane] = Ts[j][lane];
  }
  __syncthreads();
  // pass B: stage transposed tile, write P0T
#pragma unroll
  for (int a = 0; a < 4; ++a)
#pragma unroll
    for (int e = 0; e < 4; ++e)
      Ts[tx * 4 + e][ty * 4 + a] = acc[a][e];
  __syncthreads();
  {
    const int lane = tid & 63, w = tid >> 6;
    float* P0Tb = P0T + (size_t)b * NP1 * LDT;
    for (int j = w; j < 64; j += 4)
      P0Tb[(size_t)(col0 + j) * LDT + row0 + lane] = Ts[j][lane];
  }
}

// ------------------------------------------------------- dustbin borders ---
__global__ __launch_bounds__(1024) void fill_dustbin_kernel(const float* __restrict__ dustbin,
                                                            float* __restrict__ P0,
                                                            float* __restrict__ P0T) {
  const int b = blockIdx.x, tid = threadIdx.x;
  const float d = dustbin[0];
  const float dv = expf(-5.0f * fminf(fmaxf(-d, -3.0f), 3.0f));
  float* P0b = P0 + (size_t)b * NP1 * NP1;
  float* P0Tb = P0T + (size_t)b * NP1 * LDT;
  for (int j = tid; j < NP1; j += 1024) {
    P0b[(size_t)NN * NP1 + j] = dv;   // dustbin row
    P0b[(size_t)j * NP1 + NN] = dv;   // dustbin col
    P0Tb[(size_t)NN * LDT + j] = dv;
    P0Tb[(size_t)j * LDT + NN] = dv;
  }
}

// ----------------------------------------------------------- init r, c -----
__global__ __launch_bounds__(256) void init_rc_kernel(const double* __restrict__ partZ,
                                                      const float* __restrict__ dustbin,
                                                      float* __restrict__ rbuf,
                                                      float* __restrict__ cbuf) {
  const int b = blockIdx.x, tid = threadIdx.x;
  __shared__ double red[256];
  red[tid] = partZ[b * 256 + tid];
  __syncthreads();
#pragma unroll
  for (int o = 128; o; o >>= 1) {
    if (tid < o) red[tid] += red[tid + o];
    __syncthreads();
  }
  const float d = dustbin[0];
  const float dv = expf(-5.0f * fminf(fmaxf(-d, -3.0f), 3.0f));
  const double Z = red[0] + (double)dv * (double)(2 * NP1 - 1);
  const float rv = (float)(1.0 / Z);
  for (int i = tid; i < NP1; i += 256) {
    rbuf[b * NP1 + i] = rv;   // buffer 0
    cbuf[b * NP1 + i] = 1.0f; // buffer 0
  }
}

// -------------------------------------------- 100 Sinkhorn iterations ------
// P_t = diag(r) * P0 * diag(c).  Per step (both from OLD r,c):
//   u_i = (P0 c)_i   -> r'_i = ab_i / u_i
//   v_j = (P0^T r)_j -> c'_j = ab_j / v_j
// 256 blocks x 1024 thr (1 block/CU — proven-sound cooperative residency).
// Each wave owns rows i0+wv and i0+wv+16: 4 concurrent dot chains x 8-deep
// register staging = 32 independent coalesced loads in flight per wave.
__global__ __launch_bounds__(1024) void sinkhorn_kernel(const float* __restrict__ P0,
                                                        const float* __restrict__ P0T,
                                                        float* __restrict__ rbuf,
                                                        float* __restrict__ cbuf) {
  cg::grid_group grid = cg::this_grid();
  const int blk = blockIdx.x;
  const int b = blk >> 5, s = blk & 31;
  const int i0 = s * 32;
  const float* P0b = P0 + (size_t)b * NP1 * NP1;
  const float* P0Tb = P0T + (size_t)b * NP1 * LDT;
  __shared__ float sc[NP1];
  __shared__ float sr[NP1];
  const int tid = threadIdx.x;
  const int lane = tid & 63;
  const int wv = tid >> 6;  // 16 waves
  const int r0 = i0 + wv;
  const int r1 = i0 + wv + 16;
  const bool doDustbin = (s == 31 && wv == 0);
  const float* u0p = P0b + (size_t)r0 * NP1;
  const float* v0p = P0Tb + (size_t)r0 * LDT;
  const float* u1p = P0b + (size_t)r1 * NP1;
  const float* v1p = P0Tb + (size_t)r1 * LDT;
  const float* udp = P0b + (size_t)NN * NP1;
  const float* vdp = P0Tb + (size_t)NN * LDT;

  for (int t = 0; t < NSTEPS; ++t) {
    const int pin = t & 1;
    const float* rin = rbuf + pin * NB * NP1 + b * NP1;
    const float* cin = cbuf + pin * NB * NP1 + b * NP1;
    float* rout = rbuf + (pin ^ 1) * NB * NP1 + b * NP1;
    float* cout = cbuf + (pin ^ 1) * NB * NP1 + b * NP1;
    for (int j = tid; j < NP1; j += 1024) { sc[j] = cin[j]; sr[j] = rin[j]; }
    __syncthreads();

    double aU0 = 0.0, aV0 = 0.0, aU1 = 0.0, aV1 = 0.0;
#pragma unroll
    for (int kb = 0; kb < 2; ++kb) {
      float u0[8], v0[8], u1[8], v1[8];
#pragma unroll
      for (int k = 0; k < 8; ++k) {
        const int j = lane + ((kb * 8 + k) << 6);
        u0[k] = u0p[j]; v0[k] = v0p[j];
        u1[k] = u1p[j]; v1[k] = v1p[j];
      }
#pragma unroll
      for (int k = 0; k < 8; ++k) {
        const int j = lane + ((kb * 8 + k) << 6);
        const double cj = (double)sc[j], rj = (double)sr[j];
        aU0 += (double)u0[k] * cj; aV0 += (double)v0[k] * rj;
        aU1 += (double)u1[k] * cj; aV1 += (double)v1[k] * rj;
      }
    }
    if (lane == 0) {
      const double cN = (double)sc[NN], rN = (double)sr[NN];
      aU0 += (double)u0p[NN] * cN; aV0 += (double)v0p[NN] * rN;
      aU1 += (double)u1p[NN] * cN; aV1 += (double)v1p[NN] * rN;
    }
#pragma unroll
    for (int o = 32; o; o >>= 1) {
      aU0 += __shfl_xor(aU0, o, 64);
      aV0 += __shfl_xor(aV0, o, 64);
      aU1 += __shfl_xor(aU1, o, 64);
      aV1 += __shfl_xor(aV1, o, 64);
    }
    if (lane == 0) {
      rout[r0] = (float)(1.0 / aU0);
      cout[r0] = (float)(1.0 / aV0);
      rout[r1] = (float)(1.0 / aU1);
      cout[r1] = (float)(1.0 / aV1);
    }
    if (doDustbin) {
      double aUd = 0.0, aVd = 0.0;
#pragma unroll
      for (int kb = 0; kb < 2; ++kb) {
        float ud[8], vd[8];
#pragma unroll
        for (int k = 0; k < 8; ++k) {
          const int j = lane + ((kb * 8 + k) << 6);
          ud[k] = udp[j]; vd[k] = vdp[j];
        }
#pragma unroll
        for (int k = 0; k < 8; ++k) {
          const int j = lane + ((kb * 8 + k) << 6);
          aUd += (double)ud[k] * (double)sc[j];
          aVd += (double)vd[k] * (double)sr[j];
        }
      }
      if (lane == 0) {
        aUd += (double)udp[NN] * (double)sc[NN];
        aVd += (double)vdp[NN] * (double)sr[NN];
      }
#pragma unroll
      for (int o = 32; o; o >>= 1) {
        aUd += __shfl_xor(aUd, o, 64);
        aVd += __shfl_xor(aVd, o, 64);
      }
      if (lane == 0) {
        rout[NN] = (float)((double)NN / aUd);
        cout[NN] = (float)((double)NN / aVd);
      }
    }
    __threadfence();
    grid.sync();
  }
}

// --------------------------------------------------------------- finalize --
__global__ __launch_bounds__(256) void finalize_kernel(float* __restrict__ P,
                                                       const float* __restrict__ rfin,
                                                       const float* __restrict__ cfin) {
  const int bi = blockIdx.x;
  const int b = bi / NP1, i = bi % NP1;
  const float rv = rfin[b * NP1 + i];
  float* row = P + (size_t)b * NP1 * NP1 + (size_t)i * NP1;
  const float* cv = cfin + b * NP1;
  for (int j = threadIdx.x; j < NP1; j += 256) row[j] = rv * row[j] * cv[j];
}

// ---------------------------------------------------------------------------
extern "C" void kernel_launch(void* const* d_in, const int* in_sizes, int n_in,
                              void* d_out, int out_size, void* d_ws, size_t ws_size,
                              hipStream_t stream) {
  const float* fA = (const float*)d_in[0];
  const float* fB = (const float*)d_in[1];
  const float* dustbin = (const float*)d_in[2];

  float* P0 = (float*)d_out;                       // scratch until finalize
  float* P0T = (float*)d_ws;                       // 8*1025*1028 floats
  float* rbuf = P0T + (size_t)NB * NP1 * LDT;      // [2][8][1025]
  float* cbuf = rbuf + 2 * NB * NP1;               // [2][8][1025]
  double* partZ = (double*)(cbuf + 2 * NB * NP1);  // [8][256]
  float* invA = (float*)(partZ + NB * 256);        // [8][1024]
  float* invB = invA + NB * NN;                    // [8][1024]

  norm_kernel<<<4096, 256, 0, stream>>>(fA, fB, invA, invB);

  dim3 g2(16, 16, NB);
  gemm_exp_kernel<<<g2, 256, 0, stream>>>(fA, fB, invA, invB, P0, P0T, partZ);

  fill_dustbin_kernel<<<NB, 1024, 0, stream>>>(dustbin, P0, P0T);
  init_rc_kernel<<<NB, 256, 0, stream>>>(partZ, dustbin, rbuf, cbuf);

  void* args[] = {(void*)&P0, (void*)&P0T, (void*)&rbuf, (void*)&cbuf};
  hipLaunchCooperativeKernel((const void*)sinkhorn_kernel, dim3(256), dim3(1024),
                             args, 0, stream);

  // NSTEPS even -> final r,c land in buffer 0
  finalize_kernel<<<NB * NP1, 256, 0, stream>>>(P0, rbuf, cbuf);
}

// Round 4
// 1258.865 us; speedup vs baseline: 9.8107x; 8.8700x over previous
//
#include <hip/hip_runtime.h>
#include <math.h>

#define NB 8
#define NN 1024
#define DD 256
#define NP1 1025
#define LDT 1028
#define NSTEPS 100

// ---------------------------------------------------------------- norms ----
__global__ __launch_bounds__(256) void norm_kernel(const float* __restrict__ fA,
                                                   const float* __restrict__ fB,
                                                   float* __restrict__ invA,
                                                   float* __restrict__ invB) {
  int gw = (blockIdx.x * 256 + threadIdx.x) >> 6;  // global wave id, 0..16383
  int lane = threadIdx.x & 63;
  const float* src;
  float* dst;
  int row;
  if (gw < NB * NN) { src = fA; dst = invA; row = gw; }
  else              { src = fB; dst = invB; row = gw - NB * NN; }
  float4 v = *(const float4*)(src + (size_t)row * DD + lane * 4);
  double ss = (double)v.x * v.x + (double)v.y * v.y + (double)v.z * v.z + (double)v.w * v.w;
#pragma unroll
  for (int o = 32; o; o >>= 1) ss += __shfl_xor(ss, o, 64);
  if (lane == 0) dst[row] = (float)(1.0 / sqrt(fmax(ss, 1e-12)));
}

// ------------------------------------------------ GEMM + exp + partial Z ---
__global__ __launch_bounds__(256) void gemm_exp_kernel(const float* __restrict__ fA,
                                                       const float* __restrict__ fB,
                                                       const float* __restrict__ invA,
                                                       const float* __restrict__ invB,
                                                       float* __restrict__ P0,
                                                       float* __restrict__ P0T,
                                                       double* __restrict__ partZ) {
  const int b = blockIdx.z, bx = blockIdx.x, by = blockIdx.y;
  const int row0 = by * 64, col0 = bx * 64;
  const int tid = threadIdx.x;
  const int tx = tid & 15, ty = tid >> 4;
  __shared__ __align__(16) float As[16][68];
  __shared__ __align__(16) float Bs[16][68];
  __shared__ __align__(16) float Ts[64][68];
  __shared__ double zred[256];
  float acc[4][4] = {{0.f}};
  const int lm = tid >> 2, kq = (tid & 3) << 2;
  const float sa = invA[b * NN + row0 + lm];
  const float sb = invB[b * NN + col0 + lm];
  const float* pA = fA + (size_t)(b * NN + row0 + lm) * DD + kq;
  const float* pB = fB + (size_t)(b * NN + col0 + lm) * DD + kq;
  for (int k0 = 0; k0 < DD; k0 += 16) {
    const float4 a4 = *(const float4*)(pA + k0);
    const float4 b4 = *(const float4*)(pB + k0);
    As[kq + 0][lm] = a4.x * sa; As[kq + 1][lm] = a4.y * sa;
    As[kq + 2][lm] = a4.z * sa; As[kq + 3][lm] = a4.w * sa;
    Bs[kq + 0][lm] = b4.x * sb; Bs[kq + 1][lm] = b4.y * sb;
    Bs[kq + 2][lm] = b4.z * sb; Bs[kq + 3][lm] = b4.w * sb;
    __syncthreads();
#pragma unroll
    for (int kk = 0; kk < 16; ++kk) {
      const float4 av = *(const float4*)&As[kk][ty * 4];
      const float4 bv = *(const float4*)&Bs[kk][tx * 4];
      const float ar[4] = {av.x, av.y, av.z, av.w};
      const float br[4] = {bv.x, bv.y, bv.z, bv.w};
#pragma unroll
      for (int a = 0; a < 4; ++a)
#pragma unroll
        for (int e = 0; e < 4; ++e)
          acc[a][e] = fmaf(ar[a], br[e], acc[a][e]);
    }
    __syncthreads();
  }
  // exp(5*clip(S,-3,3)) == exp(-5*clip(-S,-3,3))  (matches reference exactly)
  double zs = 0.0;
#pragma unroll
  for (int a = 0; a < 4; ++a)
#pragma unroll
    for (int e = 0; e < 4; ++e) {
      const float S = acc[a][e];
      const float C = fminf(fmaxf(-S, -3.0f), 3.0f);
      const float p = expf(-5.0f * C);
      acc[a][e] = p;
      zs += (double)p;
    }
  zred[tid] = zs;
  __syncthreads();
#pragma unroll
  for (int o = 128; o; o >>= 1) {
    if (tid < o) zred[tid] += zred[tid + o];
    __syncthreads();
  }
  if (tid == 0) partZ[(b * 16 + by) * 16 + bx] = zred[0];
  // pass A: stage row-major tile, write P0 coalesced
#pragma unroll
  for (int a = 0; a < 4; ++a)
#pragma unroll
    for (int e = 0; e < 4; ++e)
      Ts[ty * 4 + a][tx * 4 + e] = acc[a][e];
  __syncthreads();
  {
    const int lane = tid & 63, w = tid >> 6;
    float* P0b = P0 + (size_t)b * NP1 * NP1;
    for (int j = w; j < 64; j += 4)
      P0b[(size_t)(row0 + j) * NP1 + col0 + lane] = Ts[j][lane];
  }
  __syncthreads();
  // pass B: stage transposed tile, write P0T
#pragma unroll
  for (int a = 0; a < 4; ++a)
#pragma unroll
    for (int e = 0; e < 4; ++e)
      Ts[tx * 4 + e][ty * 4 + a] = acc[a][e];
  __syncthreads();
  {
    const int lane = tid & 63, w = tid >> 6;
    float* P0Tb = P0T + (size_t)b * NP1 * LDT;
    for (int j = w; j < 64; j += 4)
      P0Tb[(size_t)(col0 + j) * LDT + row0 + lane] = Ts[j][lane];
  }
}

// ------------------------------------------------------- dustbin borders ---
__global__ __launch_bounds__(1024) void fill_dustbin_kernel(const float* __restrict__ dustbin,
                                                            float* __restrict__ P0,
                                                            float* __restrict__ P0T) {
  const int b = blockIdx.x, tid = threadIdx.x;
  const float d = dustbin[0];
  const float dv = expf(-5.0f * fminf(fmaxf(-d, -3.0f), 3.0f));
  float* P0b = P0 + (size_t)b * NP1 * NP1;
  float* P0Tb = P0T + (size_t)b * NP1 * LDT;
  for (int j = tid; j < NP1; j += 1024) {
    P0b[(size_t)NN * NP1 + j] = dv;   // dustbin row
    P0b[(size_t)j * NP1 + NN] = dv;   // dustbin col
    P0Tb[(size_t)NN * LDT + j] = dv;
    P0Tb[(size_t)j * LDT + NN] = dv;
  }
}

// ----------------------------------------------------------- init r, c -----
__global__ __launch_bounds__(256) void init_rc_kernel(const double* __restrict__ partZ,
                                                      const float* __restrict__ dustbin,
                                                      float* __restrict__ rbuf,
                                                      float* __restrict__ cbuf) {
  const int b = blockIdx.x, tid = threadIdx.x;
  __shared__ double red[256];
  red[tid] = partZ[b * 256 + tid];
  __syncthreads();
#pragma unroll
  for (int o = 128; o; o >>= 1) {
    if (tid < o) red[tid] += red[tid + o];
    __syncthreads();
  }
  const float d = dustbin[0];
  const float dv = expf(-5.0f * fminf(fmaxf(-d, -3.0f), 3.0f));
  const double Z = red[0] + (double)dv * (double)(2 * NP1 - 1);
  const float rv = (float)(1.0 / Z);
  for (int i = tid; i < NP1; i += 256) {
    rbuf[b * NP1 + i] = rv;   // buffer 0
    cbuf[b * NP1 + i] = 1.0f; // buffer 0
  }
}

// --------------------------------------------- one Sinkhorn step kernel ----
// P_t = diag(r) * P0 * diag(c).  Per step (both from OLD r,c):
//   u_i = (P0 c)_i   -> r'_i = ab_i / u_i     (type 0 blocks)
//   v_j = (P0^T r)_j -> c'_j = ab_j / v_j     (type 1 blocks)
// Grid (129, 16): y -> (batch, type); x -> 8-row slab. 4 waves/block, each
// wave owns 2 rows with 16-deep register staging (32 loads in flight).
// Kernel boundary = global sync (no grid.sync, no cooperative launch).
__global__ __launch_bounds__(256) void step_kernel(const float* __restrict__ P0,
                                                   const float* __restrict__ P0T,
                                                   const float* __restrict__ rin,
                                                   const float* __restrict__ cin,
                                                   float* __restrict__ rout,
                                                   float* __restrict__ cout) {
  const int by = blockIdx.y;
  const int b = by >> 1;
  const int type = by & 1;  // 0: u-pass (P0 rows x c), 1: v-pass (P0T rows x r)
  const int wv = threadIdx.x >> 6;
  const int lane = threadIdx.x & 63;

  const float* M = type ? (P0T + (size_t)b * NP1 * LDT) : (P0 + (size_t)b * NP1 * NP1);
  const size_t ld = type ? LDT : NP1;
  const float* vec = (type ? rin : cin) + b * NP1;
  float* out = (type ? cout : rout) + b * NP1;

  const int rowA = blockIdx.x * 8 + wv;
  const int rowB = rowA + 4;
  const int rA = min(rowA, NN);  // clamp: guard rows read dustbin row, discarded
  const int rB = min(rowB, NN);
  const float* pA = M + (size_t)rA * ld;
  const float* pB = M + (size_t)rB * ld;

  double accA = 0.0, accB = 0.0;
  float stA[16], stB[16];
#pragma unroll
  for (int k = 0; k < 16; ++k) {
    const int j = lane + (k << 6);
    stA[k] = pA[j];
    stB[k] = pB[j];
  }
#pragma unroll
  for (int k = 0; k < 16; ++k) {
    const int j = lane + (k << 6);
    const double vj = (double)vec[j];
    accA += (double)stA[k] * vj;
    accB += (double)stB[k] * vj;
  }
  if (lane == 0) {
    const double vN = (double)vec[NN];
    accA += (double)pA[NN] * vN;
    accB += (double)pB[NN] * vN;
  }
#pragma unroll
  for (int o = 32; o; o >>= 1) {
    accA += __shfl_xor(accA, o, 64);
    accB += __shfl_xor(accB, o, 64);
  }
  if (lane == 0) {
    if (rowA <= NN) out[rowA] = (float)((rowA == NN ? (double)NN : 1.0) / accA);
    if (rowB <= NN) out[rowB] = (float)((rowB == NN ? (double)NN : 1.0) / accB);
  }
}

// --------------------------------------------------------------- finalize --
__global__ __launch_bounds__(256) void finalize_kernel(float* __restrict__ P,
                                                       const float* __restrict__ rfin,
                                                       const float* __restrict__ cfin) {
  const int bi = blockIdx.x;
  const int b = bi / NP1, i = bi % NP1;
  const float rv = rfin[b * NP1 + i];
  float* row = P + (size_t)b * NP1 * NP1 + (size_t)i * NP1;
  const float* cv = cfin + b * NP1;
  for (int j = threadIdx.x; j < NP1; j += 256) row[j] = rv * row[j] * cv[j];
}

// ---------------------------------------------------------------------------
extern "C" void kernel_launch(void* const* d_in, const int* in_sizes, int n_in,
                              void* d_out, int out_size, void* d_ws, size_t ws_size,
                              hipStream_t stream) {
  const float* fA = (const float*)d_in[0];
  const float* fB = (const float*)d_in[1];
  const float* dustbin = (const float*)d_in[2];

  float* P0 = (float*)d_out;                       // scratch until finalize
  float* P0T = (float*)d_ws;                       // 8*1025*1028 floats
  float* rbuf = P0T + (size_t)NB * NP1 * LDT;      // [2][8][1025]
  float* cbuf = rbuf + 2 * NB * NP1;               // [2][8][1025]
  double* partZ = (double*)(cbuf + 2 * NB * NP1);  // [8][256]
  float* invA = (float*)(partZ + NB * 256);        // [8][1024]
  float* invB = invA + NB * NN;                    // [8][1024]

  norm_kernel<<<4096, 256, 0, stream>>>(fA, fB, invA, invB);

  dim3 g2(16, 16, NB);
  gemm_exp_kernel<<<g2, 256, 0, stream>>>(fA, fB, invA, invB, P0, P0T, partZ);

  fill_dustbin_kernel<<<NB, 1024, 0, stream>>>(dustbin, P0, P0T);
  init_rc_kernel<<<NB, 256, 0, stream>>>(partZ, dustbin, rbuf, cbuf);

  float* r0 = rbuf;
  float* c0 = cbuf;
  float* r1 = rbuf + NB * NP1;
  float* c1 = cbuf + NB * NP1;
  const dim3 gs(129, 16);
  for (int t = 0; t < NSTEPS; ++t) {
    if ((t & 1) == 0)
      step_kernel<<<gs, 256, 0, stream>>>(P0, P0T, r0, c0, r1, c1);
    else
      step_kernel<<<gs, 256, 0, stream>>>(P0, P0T, r1, c1, r0, c0);
  }

  // NSTEPS even -> final r,c land in buffer 0
  finalize_kernel<<<NB * NP1, 256, 0, stream>>>(P0, r0, c0);
}

// Round 5
// 1008.688 us; speedup vs baseline: 12.2440x; 1.2480x over previous
//
#include <hip/hip_runtime.h>
#include <math.h>
#include <stdint.h>

#define NB 8
#define NN 1024
#define DD 256
#define NP1 1025
#define NSTEPS 100

// ---------------------------------------------------------------- norms ----
__global__ __launch_bounds__(256) void norm_kernel(const float* __restrict__ fA,
                                                   const float* __restrict__ fB,
                                                   float* __restrict__ invA,
                                                   float* __restrict__ invB) {
  int gw = (blockIdx.x * 256 + threadIdx.x) >> 6;  // global wave id, 0..16383
  int lane = threadIdx.x & 63;
  const float* src;
  float* dst;
  int row;
  if (gw < NB * NN) { src = fA; dst = invA; row = gw; }
  else              { src = fB; dst = invB; row = gw - NB * NN; }
  float4 v = *(const float4*)(src + (size_t)row * DD + lane * 4);
  double ss = (double)v.x * v.x + (double)v.y * v.y + (double)v.z * v.z + (double)v.w * v.w;
#pragma unroll
  for (int o = 32; o; o >>= 1) ss += __shfl_xor(ss, o, 64);
  if (lane == 0) dst[row] = (float)(1.0 / sqrt(fmax(ss, 1e-12)));
}

// ------------------------------------------------ GEMM + exp + partial Z ---
// 1D grid 2048 blocks: b = id%8 (XCD pin), tile = id/8 -> (bx, by).
__global__ __launch_bounds__(256) void gemm_exp_kernel(const float* __restrict__ fA,
                                                       const float* __restrict__ fB,
                                                       const float* __restrict__ invA,
                                                       const float* __restrict__ invB,
                                                       float* __restrict__ P0,
                                                       double* __restrict__ partZ) {
  const int id = blockIdx.x;
  const int b = id & 7;
  const int tile = id >> 3;
  const int bx = tile & 15, by = tile >> 4;
  const int row0 = by * 64, col0 = bx * 64;
  const int tid = threadIdx.x;
  const int tx = tid & 15, ty = tid >> 4;
  __shared__ __align__(16) float As[16][68];
  __shared__ __align__(16) float Bs[16][68];
  __shared__ __align__(16) float Ts[64][68];
  __shared__ double zred[256];
  float acc[4][4] = {{0.f}};
  const int lm = tid >> 2, kq = (tid & 3) << 2;
  const float sa = invA[b * NN + row0 + lm];
  const float sb = invB[b * NN + col0 + lm];
  const float* pA = fA + (size_t)(b * NN + row0 + lm) * DD + kq;
  const float* pB = fB + (size_t)(b * NN + col0 + lm) * DD + kq;
  for (int k0 = 0; k0 < DD; k0 += 16) {
    const float4 a4 = *(const float4*)(pA + k0);
    const float4 b4 = *(const float4*)(pB + k0);
    As[kq + 0][lm] = a4.x * sa; As[kq + 1][lm] = a4.y * sa;
    As[kq + 2][lm] = a4.z * sa; As[kq + 3][lm] = a4.w * sa;
    Bs[kq + 0][lm] = b4.x * sb; Bs[kq + 1][lm] = b4.y * sb;
    Bs[kq + 2][lm] = b4.z * sb; Bs[kq + 3][lm] = b4.w * sb;
    __syncthreads();
#pragma unroll
    for (int kk = 0; kk < 16; ++kk) {
      const float4 av = *(const float4*)&As[kk][ty * 4];
      const float4 bv = *(const float4*)&Bs[kk][tx * 4];
      const float ar[4] = {av.x, av.y, av.z, av.w};
      const float br[4] = {bv.x, bv.y, bv.z, bv.w};
#pragma unroll
      for (int a = 0; a < 4; ++a)
#pragma unroll
        for (int e = 0; e < 4; ++e)
          acc[a][e] = fmaf(ar[a], br[e], acc[a][e]);
    }
    __syncthreads();
  }
  // exp(5*clip(S,-3,3)) == exp(-5*clip(-S,-3,3))  (matches reference exactly)
  double zs = 0.0;
#pragma unroll
  for (int a = 0; a < 4; ++a)
#pragma unroll
    for (int e = 0; e < 4; ++e) {
      const float S = acc[a][e];
      const float C = fminf(fmaxf(-S, -3.0f), 3.0f);
      const float p = expf(-5.0f * C);
      acc[a][e] = p;
      zs += (double)p;
    }
  zred[tid] = zs;
  __syncthreads();
#pragma unroll
  for (int o = 128; o; o >>= 1) {
    if (tid < o) zred[tid] += zred[tid + o];
    __syncthreads();
  }
  if (tid == 0) partZ[(b * 16 + by) * 16 + bx] = zred[0];
  // stage row-major tile, write P0 coalesced
#pragma unroll
  for (int a = 0; a < 4; ++a)
#pragma unroll
    for (int e = 0; e < 4; ++e)
      Ts[ty * 4 + a][tx * 4 + e] = acc[a][e];
  __syncthreads();
  {
    const int lane = tid & 63, w = tid >> 6;
    float* P0b = P0 + (size_t)b * NP1 * NP1;
    for (int j = w; j < 64; j += 4)
      P0b[(size_t)(row0 + j) * NP1 + col0 + lane] = Ts[j][lane];
  }
}

// ------------------------------------------------------- dustbin borders ---
__global__ __launch_bounds__(1024) void fill_dustbin_kernel(const float* __restrict__ dustbin,
                                                            float* __restrict__ P0) {
  const int b = blockIdx.x, tid = threadIdx.x;
  const float d = dustbin[0];
  const float dv = expf(-5.0f * fminf(fmaxf(-d, -3.0f), 3.0f));
  float* P0b = P0 + (size_t)b * NP1 * NP1;
  for (int j = tid; j < NP1; j += 1024) {
    P0b[(size_t)NN * NP1 + j] = dv;   // dustbin row
    P0b[(size_t)j * NP1 + NN] = dv;   // dustbin col (corner written twice, same value)
  }
}

// ------------------------------------------------------- init r0, B bufs ---
__global__ __launch_bounds__(256) void init_rc_kernel(const double* __restrict__ partZ,
                                                      float* __restrict__ r0,
                                                      double* __restrict__ Binit,
                                                      double* __restrict__ Bzero) {
  const int b = blockIdx.x, tid = threadIdx.x;
  __shared__ double red[256];
  red[tid] = partZ[b * 256 + tid];
  __syncthreads();
#pragma unroll
  for (int o = 128; o; o >>= 1) {
    if (tid < o) red[tid] += red[tid + o];
    __syncthreads();
  }
  const double Z = red[0];
  const float rv = (float)(1.0 / Z);
  for (int i = tid; i < NP1; i += 256) {
    r0[b * NP1 + i] = rv;
    Binit[b * NP1 + i] = (i == NN) ? (double)NN : 1.0;  // so c_0 = ab/Binit = 1
    Bzero[b * NP1 + i] = 0.0;
  }
}

// --------------------------------------------- one Sinkhorn step kernel ----
// Single read of P0 per step. P_t = diag(r) * P0 * diag(c), c_t = ab/B_prev.
//   u_i = (P0 c_t)_i          -> r_{t+1},i = ab_i / u_i   (plain write)
//   B_t[j] += sum_i r_t,i P0[i,j]  (f32 block partials -> f64 atomicAdd)
// 520 blocks x 512 thr: b = id%8 (XCD pin), slab = id/8 (16 rows), 8 waves x
// 2 rows each, 16-deep register staging.
__global__ __launch_bounds__(512) void step_kernel(const float* __restrict__ P0,
                                                   const float* __restrict__ rin,
                                                   float* __restrict__ rout,
                                                   const double* __restrict__ Bprev,
                                                   double* __restrict__ Bacc,
                                                   double* __restrict__ Bzero) {
  const int id = blockIdx.x;
  const int b = id & 7;   // XCD pin: batch = bid % 8
  const int s = id >> 3;  // slab 0..64
  const int tid = threadIdx.x;
  const int lane = tid & 63;
  const int wv = tid >> 6;  // 0..7

  __shared__ float c_lds[NP1];
  __shared__ float part_lds[8][NP1];

  // zero next step's accumulator buffer (unused this step): 16 doubles/block
  {
    const int base = id * 16;
    if (tid < 16) {
      const int idx = base + tid;
      if (idx < NB * NP1) Bzero[idx] = 0.0;
    }
  }
  // c_t = ab / Bprev (rounded to f32, matching prior passing versions)
  const double* Bp = Bprev + b * NP1;
  for (int j = tid; j < NP1; j += 512) {
    const double ab = (j == NN) ? (double)NN : 1.0;
    c_lds[j] = (float)(ab / Bp[j]);
  }
  __syncthreads();

  const float* P0b = P0 + (size_t)b * NP1 * NP1;
  const float* rv_in = rin + b * NP1;
  const int rowA = s * 16 + wv;
  const int rowB = rowA + 8;
  const bool vA = rowA < NP1;
  const bool vB = rowB < NP1;
  const int rA = vA ? rowA : NN;  // clamp: guard rows read row NN, weight 0
  const int rB = vB ? rowB : NN;
  const float wA = vA ? rv_in[rowA] : 0.0f;
  const float wB = vB ? rv_in[rowB] : 0.0f;
  const float* pA = P0b + (size_t)rA * NP1;
  const float* pB = P0b + (size_t)rB * NP1;

  double dotA = 0.0, dotB = 0.0;
  float part[16];
#pragma unroll
  for (int k = 0; k < 16; ++k) part[k] = 0.0f;

  float stA[16], stB[16];
#pragma unroll
  for (int k = 0; k < 16; ++k) {
    const int j = lane + (k << 6);
    stA[k] = pA[j];
    stB[k] = pB[j];
  }
#pragma unroll
  for (int k = 0; k < 16; ++k) {
    const int j = lane + (k << 6);
    const double cj = (double)c_lds[j];
    dotA += (double)stA[k] * cj;
    dotB += (double)stB[k] * cj;
    part[k] = fmaf(wA, stA[k], fmaf(wB, stB[k], part[k]));
  }
  float ptail = 0.0f;
  if (lane == 0) {
    const float aT = pA[NN], bT = pB[NN];
    const double cN = (double)c_lds[NN];
    dotA += (double)aT * cN;
    dotB += (double)bT * cN;
    ptail = wA * aT + wB * bT;
  }
  // wave-reduce the two row dots
#pragma unroll
  for (int o = 32; o; o >>= 1) {
    dotA += __shfl_xor(dotA, o, 64);
    dotB += __shfl_xor(dotB, o, 64);
  }
  if (lane == 0) {
    float* ro = rout + b * NP1;
    if (vA) ro[rowA] = (float)((rowA == NN ? (double)NN : 1.0) / dotA);
    if (vB) ro[rowB] = (float)((rowB == NN ? (double)NN : 1.0) / dotB);
  }
  // column partials: LDS combine across 8 waves, then one f64 atomic per col
#pragma unroll
  for (int k = 0; k < 16; ++k) part_lds[wv][lane + (k << 6)] = part[k];
  if (lane == 0) part_lds[wv][NN] = ptail;
  __syncthreads();
  double* Ba = Bacc + b * NP1;
  for (int j = tid; j < NP1; j += 512) {
    const float s0 = ((part_lds[0][j] + part_lds[1][j]) + (part_lds[2][j] + part_lds[3][j])) +
                     ((part_lds[4][j] + part_lds[5][j]) + (part_lds[6][j] + part_lds[7][j]));
    atomicAdd(Ba + j, (double)s0);
  }
}

// ----------------------------------------------------- final c from B ------
__global__ __launch_bounds__(256) void cfinal_kernel(const double* __restrict__ Bfin,
                                                     float* __restrict__ cfin) {
  const int b = blockIdx.x;
  for (int j = threadIdx.x; j < NP1; j += 256)
    cfin[b * NP1 + j] = (float)(((j == NN) ? (double)NN : 1.0) / Bfin[b * NP1 + j]);
}

// --------------------------------------------------------------- finalize --
__global__ __launch_bounds__(256) void finalize_kernel(float* __restrict__ P,
                                                       const float* __restrict__ rfin,
                                                       const float* __restrict__ cfin) {
  const int bi = blockIdx.x;
  const int b = bi & 7, i = bi >> 3;  // XCD pin: batch = bid % 8
  const float rv = rfin[b * NP1 + i];
  float* row = P + (size_t)b * NP1 * NP1 + (size_t)i * NP1;
  const float* cv = cfin + b * NP1;
  for (int j = threadIdx.x; j < NP1; j += 256) row[j] = rv * row[j] * cv[j];
}

// ---------------------------------------------------------------------------
extern "C" void kernel_launch(void* const* d_in, const int* in_sizes, int n_in,
                              void* d_out, int out_size, void* d_ws, size_t ws_size,
                              hipStream_t stream) {
  const float* fA = (const float*)d_in[0];
  const float* fB = (const float*)d_in[1];
  const float* dustbin = (const float*)d_in[2];

  float* P0 = (float*)d_out;  // scratch until finalize (in-place)

  float* rbuf = (float*)d_ws;                 // [2][8][1025] f32
  float* cfin = rbuf + 2 * NB * NP1;          // [8][1025] f32
  double* Bbuf = (double*)(((uintptr_t)(cfin + NB * NP1) + 15) & ~(uintptr_t)15);  // [3][8][1025] f64
  double* partZ = Bbuf + 3 * NB * NP1;        // [8][256] f64
  float* invA = (float*)(partZ + NB * 256);   // [8][1024]
  float* invB = invA + NB * NN;               // [8][1024]

  norm_kernel<<<4096, 256, 0, stream>>>(fA, fB, invA, invB);
  gemm_exp_kernel<<<2048, 256, 0, stream>>>(fA, fB, invA, invB, P0, partZ);
  fill_dustbin_kernel<<<NB, 1024, 0, stream>>>(dustbin, P0);
  // r_0 -> rbuf[0]; B "prev" for t=0 -> Bbuf[2] (c_0 = 1); zero Bbuf[0]
  init_rc_kernel<<<NB, 256, 0, stream>>>(partZ, rbuf, Bbuf + 2 * NB * NP1, Bbuf);

  // step t: reads r[t%2], B[(t+2)%3]; writes r[(t+1)%2]; accumulates B[t%3];
  //         zeroes B[(t+1)%3] (for step t+1).
  for (int t = 0; t < NSTEPS; ++t) {
    float* rin = rbuf + (t & 1) * NB * NP1;
    float* rout = rbuf + ((t + 1) & 1) * NB * NP1;
    double* Bprev = Bbuf + ((t + 2) % 3) * NB * NP1;
    double* Bacc = Bbuf + (t % 3) * NB * NP1;
    double* Bzero = Bbuf + ((t + 1) % 3) * NB * NP1;
    step_kernel<<<520, 512, 0, stream>>>(P0, rin, rout, Bprev, Bacc, Bzero);
  }

  // after t=99: r_100 in rbuf[0]; B_99 (col sums) in Bbuf[99%3=0]
  cfinal_kernel<<<NB, 256, 0, stream>>>(Bbuf, cfin);
  finalize_kernel<<<NB * NP1, 256, 0, stream>>>(P0, rbuf, cfin);
}

// Round 7
// 967.579 us; speedup vs baseline: 12.7642x; 1.0425x over previous
//
#include <hip/hip_runtime.h>
#include <math.h>
#include <stdint.h>

#define NB 8
#define NN 1024
#define DD 256
#define NP1 1025
#define LDP 1028   // padded row stride for P0 in ws (16B-aligned rows)
#define NSTEPS 100

// ---------------------------------------------------------------- norms ----
__global__ __launch_bounds__(256) void norm_kernel(const float* __restrict__ fA,
                                                   const float* __restrict__ fB,
                                                   float* __restrict__ invA,
                                                   float* __restrict__ invB) {
  int gw = (blockIdx.x * 256 + threadIdx.x) >> 6;  // global wave id, 0..16383
  int lane = threadIdx.x & 63;
  const float* src;
  float* dst;
  int row;
  if (gw < NB * NN) { src = fA; dst = invA; row = gw; }
  else              { src = fB; dst = invB; row = gw - NB * NN; }
  float4 v = *(const float4*)(src + (size_t)row * DD + lane * 4);
  double ss = (double)v.x * v.x + (double)v.y * v.y + (double)v.z * v.z + (double)v.w * v.w;
#pragma unroll
  for (int o = 32; o; o >>= 1) ss += __shfl_xor(ss, o, 64);
  if (lane == 0) dst[row] = (float)(1.0 / sqrt(fmax(ss, 1e-12)));
}

// ------------------------------------------------ GEMM + exp + partial Z ---
// 1D grid 2048 blocks: b = id%8 (XCD pin), tile = id/8 -> (bx, by).
// Direct aligned float4 stores to padded P0 (no LDS transpose staging).
__global__ __launch_bounds__(256) void gemm_exp_kernel(const float* __restrict__ fA,
                                                       const float* __restrict__ fB,
                                                       const float* __restrict__ invA,
                                                       const float* __restrict__ invB,
                                                       float* __restrict__ P0,
                                                       double* __restrict__ partZ) {
  const int id = blockIdx.x;
  const int b = id & 7;
  const int tile = id >> 3;
  const int bx = tile & 15, by = tile >> 4;
  const int row0 = by * 64, col0 = bx * 64;
  const int tid = threadIdx.x;
  const int tx = tid & 15, ty = tid >> 4;
  __shared__ __align__(16) float As[16][68];
  __shared__ __align__(16) float Bs[16][68];
  __shared__ double zred[256];
  float acc[4][4] = {{0.f}};
  const int lm = tid >> 2, kq = (tid & 3) << 2;
  const float sa = invA[b * NN + row0 + lm];
  const float sb = invB[b * NN + col0 + lm];
  const float* pA = fA + (size_t)(b * NN + row0 + lm) * DD + kq;
  const float* pB = fB + (size_t)(b * NN + col0 + lm) * DD + kq;
  for (int k0 = 0; k0 < DD; k0 += 16) {
    const float4 a4 = *(const float4*)(pA + k0);
    const float4 b4 = *(const float4*)(pB + k0);
    As[kq + 0][lm] = a4.x * sa; As[kq + 1][lm] = a4.y * sa;
    As[kq + 2][lm] = a4.z * sa; As[kq + 3][lm] = a4.w * sa;
    Bs[kq + 0][lm] = b4.x * sb; Bs[kq + 1][lm] = b4.y * sb;
    Bs[kq + 2][lm] = b4.z * sb; Bs[kq + 3][lm] = b4.w * sb;
    __syncthreads();
#pragma unroll
    for (int kk = 0; kk < 16; ++kk) {
      const float4 av = *(const float4*)&As[kk][ty * 4];
      const float4 bv = *(const float4*)&Bs[kk][tx * 4];
      const float ar[4] = {av.x, av.y, av.z, av.w};
      const float br[4] = {bv.x, bv.y, bv.z, bv.w};
#pragma unroll
      for (int a = 0; a < 4; ++a)
#pragma unroll
        for (int e = 0; e < 4; ++e)
          acc[a][e] = fmaf(ar[a], br[e], acc[a][e]);
    }
    __syncthreads();
  }
  // exp(5*clip(S,-3,3)) == exp(-5*clip(-S,-3,3))  (matches reference exactly)
  double zs = 0.0;
#pragma unroll
  for (int a = 0; a < 4; ++a)
#pragma unroll
    for (int e = 0; e < 4; ++e) {
      const float S = acc[a][e];
      const float C = fminf(fmaxf(-S, -3.0f), 3.0f);
      const float p = expf(-5.0f * C);
      acc[a][e] = p;
      zs += (double)p;
    }
  // direct float4 stores (row base 16B-aligned: LDP*4 = 4112 % 16 == 0)
  {
    float* P0b = P0 + (size_t)b * NP1 * LDP;
#pragma unroll
    for (int a = 0; a < 4; ++a) {
      float4 v;
      v.x = acc[a][0]; v.y = acc[a][1]; v.z = acc[a][2]; v.w = acc[a][3];
      *(float4*)(P0b + (size_t)(row0 + ty * 4 + a) * LDP + col0 + tx * 4) = v;
    }
  }
  zred[tid] = zs;
  __syncthreads();
#pragma unroll
  for (int o = 128; o; o >>= 1) {
    if (tid < o) zred[tid] += zred[tid + o];
    __syncthreads();
  }
  if (tid == 0) partZ[(b * 16 + by) * 16 + bx] = zred[0];
}

// ------------------------------------------------------- dustbin borders ---
__global__ __launch_bounds__(1024) void fill_dustbin_kernel(const float* __restrict__ dustbin,
                                                            float* __restrict__ P0) {
  const int b = blockIdx.x, tid = threadIdx.x;
  const float d = dustbin[0];
  const float dv = expf(-5.0f * fminf(fmaxf(-d, -3.0f), 3.0f));
  float* P0b = P0 + (size_t)b * NP1 * LDP;
  for (int j = tid; j < NP1; j += 1024) {
    P0b[(size_t)NN * LDP + j] = dv;   // dustbin row
    P0b[(size_t)j * LDP + NN] = dv;   // dustbin col (corner written twice, same value)
  }
}

// ------------------------------------------------------- init r0, B bufs ---
__global__ __launch_bounds__(256) void init_rc_kernel(const double* __restrict__ partZ,
                                                      float* __restrict__ r0,
                                                      double* __restrict__ Binit,
                                                      double* __restrict__ Bzero) {
  const int b = blockIdx.x, tid = threadIdx.x;
  __shared__ double red[256];
  red[tid] = partZ[b * 256 + tid];
  __syncthreads();
#pragma unroll
  for (int o = 128; o; o >>= 1) {
    if (tid < o) red[tid] += red[tid + o];
    __syncthreads();
  }
  const double Z = red[0];
  const float rv = (float)(1.0 / Z);
  for (int i = tid; i < NP1; i += 256) {
    r0[b * NP1 + i] = rv;
    Binit[b * NP1 + i] = (i == NN) ? (double)NN : 1.0;  // so c_0 = ab/Binit = 1
    Bzero[b * NP1 + i] = 0.0;
  }
}

// --------------------------------------------- one Sinkhorn step kernel ----
// Single read of P0 per step. P_t = diag(r) * P0 * diag(c), c_t = ab/B_prev.
//   u_i = (P0 c_t)_i              -> r_{t+1},i = ab_i / u_i  (plain write)
//   B_t[j] += sum_i r_t,i P0[i,j] (f32 block partials -> f64 atomicAdd)
// 512 blocks x 512 thr (2/CU exactly): b = id%8 (XCD pin), slab = id/8 (16
// rows, 8 waves x 2 rows, float4 staged). Wave (s=63,wv=7) also does the
// dustbin row 1024. Global loads issued BEFORE the c/B prologue to hide
// latency under it.
__global__ __launch_bounds__(512, 4) void step_kernel(const float* __restrict__ P0,
                                                      const float* __restrict__ rin,
                                                      float* __restrict__ rout,
                                                      const double* __restrict__ Bprev,
                                                      double* __restrict__ Bacc,
                                                      double* __restrict__ Bzero) {
  const int id = blockIdx.x;
  const int b = id & 7;   // XCD pin: batch = bid % 8
  const int s = id >> 3;  // slab 0..63
  const int tid = threadIdx.x;
  const int lane = tid & 63;
  const int wv = tid >> 6;  // 0..7

  __shared__ __align__(16) double c_lds[NP1 + 3];
  __shared__ __align__(16) float part_lds[8][LDP];

  const float* P0b = P0 + (size_t)b * NP1 * LDP;
  const float* rv_in = rin + b * NP1;
  const int rowA = s * 16 + wv;      // 0..1015
  const int rowB = rowA + 8;         // 8..1023
  const bool special = (s == 63 && wv == 7);  // also owns dustbin row 1024
  const float wA = rv_in[rowA];
  const float wB = rv_in[rowB];
  const float4* pA4 = (const float4*)(P0b + (size_t)rowA * LDP);
  const float4* pB4 = (const float4*)(P0b + (size_t)rowB * LDP);
  const float4* pC4 = (const float4*)(P0b + (size_t)NN * LDP);

  // ---- issue all global row loads first (latency hides under prologue) ----
  float4 a4[4], b4[4];
#pragma unroll
  for (int k = 0; k < 4; ++k) {
    a4[k] = pA4[lane + (k << 6)];
    b4[k] = pB4[lane + (k << 6)];
  }
  float aT = 0.f, bT = 0.f;
  if (lane == 0) {
    aT = ((const float*)pA4)[NN];
    bT = ((const float*)pB4)[NN];
  }
  float4 c4[4];
  float cT = 0.f, wC = 0.f;
  if (special) {
#pragma unroll
    for (int k = 0; k < 4; ++k) c4[k] = pC4[lane + (k << 6)];
    if (lane == 0) cT = ((const float*)pC4)[NN];
    wC = rv_in[NN];
  }

  // ---- prologue: zero next-step B; compute c_t = ab/Bprev in f64 LDS ----
  // coverage: 512 blocks x 17 = 8704 >= NB*NP1 = 8200  (R6 bug: 16/block)
  if (tid < 17) {
    const int idx = id * 17 + tid;
    if (idx < NB * NP1) Bzero[idx] = 0.0;
  }
  const double* Bp = Bprev + b * NP1;
  for (int j = tid; j < NP1; j += 512)
    c_lds[j] = ((j == NN) ? (double)NN : 1.0) / Bp[j];
  __syncthreads();

  // ---- dots (f64) + column partials (f32) ----
  double dotA = 0.0, dotB = 0.0, dotC = 0.0;
  float4 part[4];
#pragma unroll
  for (int k = 0; k < 4; ++k) {
    const int j4 = lane + (k << 6);
    const double2 c01 = *(const double2*)&c_lds[4 * j4];
    const double2 c23 = *(const double2*)&c_lds[4 * j4 + 2];
    dotA += (double)a4[k].x * c01.x + (double)a4[k].y * c01.y +
            (double)a4[k].z * c23.x + (double)a4[k].w * c23.y;
    dotB += (double)b4[k].x * c01.x + (double)b4[k].y * c01.y +
            (double)b4[k].z * c23.x + (double)b4[k].w * c23.y;
    part[k].x = fmaf(wA, a4[k].x, wB * b4[k].x);
    part[k].y = fmaf(wA, a4[k].y, wB * b4[k].y);
    part[k].z = fmaf(wA, a4[k].z, wB * b4[k].z);
    part[k].w = fmaf(wA, a4[k].w, wB * b4[k].w);
    if (special) {
      dotC += (double)c4[k].x * c01.x + (double)c4[k].y * c01.y +
              (double)c4[k].z * c23.x + (double)c4[k].w * c23.y;
      part[k].x = fmaf(wC, c4[k].x, part[k].x);
      part[k].y = fmaf(wC, c4[k].y, part[k].y);
      part[k].z = fmaf(wC, c4[k].z, part[k].z);
      part[k].w = fmaf(wC, c4[k].w, part[k].w);
    }
  }
  float ptail = 0.f;
  if (lane == 0) {
    const double cN = c_lds[NN];
    dotA += (double)aT * cN;
    dotB += (double)bT * cN;
    ptail = wA * aT + wB * bT;
    if (special) { dotC += (double)cT * cN; ptail = fmaf(wC, cT, ptail); }
  }
#pragma unroll
  for (int o = 32; o; o >>= 1) {
    dotA += __shfl_xor(dotA, o, 64);
    dotB += __shfl_xor(dotB, o, 64);
  }
  if (special) {
#pragma unroll
    for (int o = 32; o; o >>= 1) dotC += __shfl_xor(dotC, o, 64);
  }
  if (lane == 0) {
    float* ro = rout + b * NP1;
    ro[rowA] = (float)(1.0 / dotA);
    ro[rowB] = (float)(1.0 / dotB);
    if (special) ro[NN] = (float)((double)NN / dotC);
  }
  // ---- combine column partials across waves, one f64 atomic per column ----
  {
    float4* pl4 = (float4*)&part_lds[wv][0];
#pragma unroll
    for (int k = 0; k < 4; ++k) pl4[lane + (k << 6)] = part[k];
    if (lane == 0) part_lds[wv][NN] = ptail;
  }
  __syncthreads();
  double* Ba = Bacc + b * NP1;
  for (int j = tid; j < NP1; j += 512) {
    const float s0 = ((part_lds[0][j] + part_lds[1][j]) + (part_lds[2][j] + part_lds[3][j])) +
                     ((part_lds[4][j] + part_lds[5][j]) + (part_lds[6][j] + part_lds[7][j]));
    atomicAdd(Ba + j, (double)s0);
  }
}

// ----------------------------------------------------- final c from B ------
__global__ __launch_bounds__(256) void cfinal_kernel(const double* __restrict__ Bfin,
                                                     float* __restrict__ cfin) {
  const int b = blockIdx.x;
  for (int j = threadIdx.x; j < NP1; j += 256)
    cfin[b * LDP + j] = (float)(((j == NN) ? (double)NN : 1.0) / Bfin[b * NP1 + j]);
}

// --------------------------------------------------------------- finalize --
// One row per block: float4 loads from padded P0/c, scalar stores to d_out.
__global__ __launch_bounds__(256) void finalize_kernel(const float* __restrict__ P0,
                                                       float* __restrict__ Pout,
                                                       const float* __restrict__ rfin,
                                                       const float* __restrict__ cfin) {
  const int bi = blockIdx.x;
  const int b = bi & 7, i = bi >> 3;  // XCD pin: batch = bid % 8
  const int tid = threadIdx.x;
  const float rv = rfin[b * NP1 + i];
  const float4* src = (const float4*)(P0 + (size_t)b * NP1 * LDP + (size_t)i * LDP);
  const float4* cv = (const float4*)(cfin + b * LDP);
  float* dst = Pout + (size_t)b * NP1 * NP1 + (size_t)i * NP1;
  const float4 p = src[tid];
  const float4 c = cv[tid];
  dst[tid * 4 + 0] = rv * p.x * c.x;
  dst[tid * 4 + 1] = rv * p.y * c.y;
  dst[tid * 4 + 2] = rv * p.z * c.z;
  dst[tid * 4 + 3] = rv * p.w * c.w;
  if (tid == 0)
    dst[NN] = rv * ((const float*)src)[NN] * cfin[b * LDP + NN];
}

// ---------------------------------------------------------------------------
extern "C" void kernel_launch(void* const* d_in, const int* in_sizes, int n_in,
                              void* d_out, int out_size, void* d_ws, size_t ws_size,
                              hipStream_t stream) {
  const float* fA = (const float*)d_in[0];
  const float* fB = (const float*)d_in[1];
  const float* dustbin = (const float*)d_in[2];

  float* Pout = (float*)d_out;                 // written only by finalize

  float* P0 = (float*)d_ws;                    // [8][1025][1028] f32, padded rows
  float* rbuf = P0 + (size_t)NB * NP1 * LDP;   // [2][8][1025] f32
  float* cfin = rbuf + 2 * NB * NP1;           // [8][1028] f32 (padded)
  double* Bbuf = (double*)(((uintptr_t)(cfin + NB * LDP) + 15) & ~(uintptr_t)15);  // [3][8][1025] f64
  double* partZ = Bbuf + 3 * NB * NP1;         // [8][256] f64
  float* invA = (float*)(partZ + NB * 256);    // [8][1024]
  float* invB = invA + NB * NN;                // [8][1024]

  norm_kernel<<<4096, 256, 0, stream>>>(fA, fB, invA, invB);
  gemm_exp_kernel<<<2048, 256, 0, stream>>>(fA, fB, invA, invB, P0, partZ);
  fill_dustbin_kernel<<<NB, 1024, 0, stream>>>(dustbin, P0);
  // r_0 -> rbuf[0]; B "prev" for t=0 -> Bbuf[2] (c_0 = 1); zero Bbuf[0]
  init_rc_kernel<<<NB, 256, 0, stream>>>(partZ, rbuf, Bbuf + 2 * NB * NP1, Bbuf);

  // step t: reads r[t%2], B[(t+2)%3]; writes r[(t+1)%2]; accumulates B[t%3];
  //         zeroes B[(t+1)%3] (for step t+1).
  for (int t = 0; t < NSTEPS; ++t) {
    float* rin = rbuf + (t & 1) * NB * NP1;
    float* rout = rbuf + ((t + 1) & 1) * NB * NP1;
    double* Bprev = Bbuf + ((t + 2) % 3) * NB * NP1;
    double* Bacc = Bbuf + (t % 3) * NB * NP1;
    double* Bzero = Bbuf + ((t + 1) % 3) * NB * NP1;
    step_kernel<<<512, 512, 0, stream>>>(P0, rin, rout, Bprev, Bacc, Bzero);
  }

  // after t=99: r_100 in rbuf[0]; B_99 (col sums) in Bbuf[99%3=0]
  cfinal_kernel<<<NB, 256, 0, stream>>>(Bbuf, cfin);
  finalize_kernel<<<NB * NP1, 256, 0, stream>>>(P0, Pout, rbuf, cfin);
}